// Round 7
// baseline (259.614 us; speedup 1.0000x reference)
//
#include <hip/hip_runtime.h>
#include <hip/hip_cooperative_groups.h>
#include <hip/hip_bf16.h>
#include <math.h>

namespace cg = cooperative_groups;

#define N_NODES 100000
#define N_EDGES 1000000
#define DIM 64
#define NCHUNK 391        // ceil(N_NODES/256) 256-node chunks
#define AGPAD 72          // LDS row stride in shorts (16-B aligned, conflict-light)
#define NHB 125           // histogram segments (LDS-private byte histograms)
#define BTHREADS 1024     // threads per build block (16 waves: latency hiding)
#define BBLOCKS (2 * NHB) // 250 build blocks: (segment, node-half) pairs
#define EPB (N_EDGES / NHB)         // 8000 edges per histogram segment
#define HWORDS ((N_NODES + 3) / 4)  // 25000 packed words per histogram
#define HALF_NODES (N_NODES / 2)    // 50000: node-range split per block
#define HWORDS_HALF (HALF_NODES / 4) // 12500 words = 50KB LDS per block

// Device dtypes (established empirically R1-R8): fp32 floats, int32 indices,
// fp32 output.
typedef __hip_bfloat16 bf16;
typedef __attribute__((ext_vector_type(8))) short short8;
typedef __attribute__((ext_vector_type(4))) float floatx4;

__device__ __forceinline__ float b2f(bf16 v) { return __bfloat162float(v); }

__device__ __forceinline__ unsigned int packbf2(float a, float b) {
    bf16 x = __float2bfloat16(a), y = __float2bfloat16(b);
    unsigned short ux = *(unsigned short*)&x, uy = *(unsigned short*)&y;
    return (unsigned int)ux | ((unsigned int)uy << 16);
}

__device__ __forceinline__ short f2bs(float v) {
    bf16 x = __float2bfloat16(v);
    return *(short*)&x;
}

__device__ __forceinline__ float2 upk(unsigned int u) {
    unsigned short lo = (unsigned short)(u & 0xffff);
    unsigned short hi = (unsigned short)(u >> 16);
    bf16 a = *(bf16*)&lo, b = *(bf16*)&hi;
    return make_float2(b2f(a), b2f(b));
}

__device__ __forceinline__ int clampN(int v) {
    return v < 0 ? 0 : (v >= N_NODES ? N_NODES - 1 : v);
}

// ---------------------------------------------------------------------------
// R7: whole CSR build fused into ONE cooperative kernel (6 launches -> 3).
// 250 blocks x 1024 threads, co-resident (1 block/CU min; 52KB LDS, 16 waves).
// Phase A: per-(segment,half) LDS byte histogram of dst -> bh dump; convert
//          x->bf16 and wt ride along (independent work, same launch).
// Phase B: grid-stride over 391 256-node chunks: fold NHB per-seg counts per
//          node (exclusive byte bases written back in place), degi totals,
//          intra-chunk exclusive scan -> rowstart, chunk sums -> chsum.
// Phase C/D: every block redundantly scans chsum[391] -> LDS bsumL (removes
//          the 1-block scan2 dispatch); block 0 persists bsum for agg/final;
//          then fill: LDS byte counters initialized with bases, ds_add_rtn
//          per in-range edge yields base+rank; csr scatter.
// Numerics and csr ordering identical to R6 (same decomposition/counters).
// Zero global atomics anywhere in the build.
// ---------------------------------------------------------------------------
__global__ __launch_bounds__(BTHREADS) void build_kernel(
        const int* __restrict__ ei,
        unsigned int* __restrict__ bh32,
        const float4* __restrict__ x4,
        uint2* __restrict__ xb4,
        const float* __restrict__ Wl0,
        const float* __restrict__ Wr0,
        short* __restrict__ wt,
        int* __restrict__ degi,
        int* __restrict__ rowstart,
        int* __restrict__ chsum,
        int* __restrict__ bsum,
        int* __restrict__ csr) {
    __shared__ unsigned int cnt[HWORDS_HALF];   // 50 KB: count + fill counters
    __shared__ int sc[512];                     // scans (chunk scan + chsum scan)
    __shared__ int bsumL[NCHUNK];               // per-block copy of chunk bases
    cg::grid_group grid = cg::this_grid();

    const int t = threadIdx.x, b = blockIdx.x;
    const int seg = b >> 1, half = b & 1;
    const int nlo = half * HALF_NODES, nhi = nlo + HALF_NODES;

    // ---- phase A: count (+ convert + wt) ----
    for (int w = t; w < HWORDS_HALF; w += BTHREADS) cnt[w] = 0u;
    __syncthreads();
    {
        const int4* dst4 = (const int4*)(ei + N_EDGES + seg * EPB);
        for (int k = t; k < EPB / 4; k += BTHREADS) {
            int4 d4 = dst4[k];
            int d;
            d = clampN(d4.x); if (d >= nlo && d < nhi) { int ld = d - nlo; atomicAdd(&cnt[ld >> 2], 1u << (8 * (ld & 3))); }
            d = clampN(d4.y); if (d >= nlo && d < nhi) { int ld = d - nlo; atomicAdd(&cnt[ld >> 2], 1u << (8 * (ld & 3))); }
            d = clampN(d4.z); if (d >= nlo && d < nhi) { int ld = d - nlo; atomicAdd(&cnt[ld >> 2], 1u << (8 * (ld & 3))); }
            d = clampN(d4.w); if (d >= nlo && d < nhi) { int ld = d - nlo; atomicAdd(&cnt[ld >> 2], 1u << (8 * (ld & 3))); }
        }
        __syncthreads();
        unsigned int* outp = bh32 + (long)seg * HWORDS + half * HWORDS_HALF;
        for (int w = t; w < HWORDS_HALF; w += BTHREADS) outp[w] = cnt[w];
        // convert share: 1.6M float4 total = 250 blocks x 6400
        const int cbase = b * 6400;
        for (int j = t; j < 6400; j += BTHREADS) {
            int idx = cbase + j;
            float4 f = x4[idx];
            xb4[idx] = make_uint2(packbf2(f.x, f.y), packbf2(f.z, f.w));
        }
        if (b == 0) {
            for (int i = t; i < 8192; i += BTHREADS) {
                int d = i >> 7, k = i & 127;
                float v = (k < 64) ? Wl0[d * 64 + k] : Wr0[d * 64 + (k - 64)];
                wt[i] = f2bs(v);
            }
        }
    }
    grid.sync();

    // ---- phase B: per-node fold + intra-chunk scan (grid-stride chunks) ----
    {
        unsigned char* bhb = (unsigned char*)bh32;
        for (int chunk = b; chunk < NCHUNK; chunk += BBLOCKS) {
            int i = chunk * 256 + t;   // t<256 active
            int v = 0;
            if (t < 256 && i < N_NODES) {
                int sum = 0;
                #pragma unroll 5
                for (int c = 0; c < NHB; ++c) {
                    long off = (long)c * (HWORDS * 4) + i;
                    int u = bhb[off];
                    bhb[off] = (unsigned char)sum;   // exclusive base for segment c
                    sum += u;
                }
                degi[i] = sum;                       // total degree
                v = sum;
            }
            if (t < 256) sc[t] = v;
            __syncthreads();
            #pragma unroll
            for (int off = 1; off < 256; off <<= 1) {
                int u = 0;
                if (t < 256 && t >= off) u = sc[t - off];
                __syncthreads();
                if (t < 256) sc[t] += u;
                __syncthreads();
            }
            if (t < 256 && i < N_NODES) rowstart[i] = sc[t] - v;  // excl within chunk
            if (t == 255) chsum[chunk] = sc[255];
            __syncthreads();
        }
    }
    grid.sync();

    // ---- phase C: redundant per-block exclusive scan of chsum -> bsumL ----
    {
        int v = 0;
        if (t < 512) {
            v = (t < NCHUNK) ? chsum[t] : 0;
            sc[t] = v;
        }
        __syncthreads();
        #pragma unroll
        for (int off = 1; off < 512; off <<= 1) {
            int u = 0;
            if (t < 512 && t >= off) u = sc[t - off];
            __syncthreads();
            if (t < 512) sc[t] += u;
            __syncthreads();
        }
        if (t < NCHUNK) {
            bsumL[t] = sc[t] - v;
            if (b == 0) bsum[t] = sc[t] - v;   // persist for agg/final
        }
    }

    // ---- phase D: fill (reload bases as counter init, ds_add_rtn -> rank) ----
    {
        const unsigned int* inp = bh32 + (long)seg * HWORDS + half * HWORDS_HALF;
        for (int w = t; w < HWORDS_HALF; w += BTHREADS) cnt[w] = inp[w];
        __syncthreads();
        const int4* srcp4 = (const int4*)(ei + seg * EPB);
        const int4* dstp4 = (const int4*)(ei + N_EDGES + seg * EPB);
        for (int k = t; k < EPB / 4; k += BTHREADS) {
            int4 s4 = srcp4[k];
            int4 d4 = dstp4[k];
            int d, ld, sv;
            unsigned int old;
            d = clampN(d4.x);
            if (d >= nlo && d < nhi) {
                ld = d - nlo; sv = clampN(s4.x);
                old = atomicAdd(&cnt[ld >> 2], 1u << (8 * (ld & 3)));
                csr[rowstart[d] + bsumL[d >> 8] + (int)((old >> (8 * (ld & 3))) & 0xffu)] = sv;
            }
            d = clampN(d4.y);
            if (d >= nlo && d < nhi) {
                ld = d - nlo; sv = clampN(s4.y);
                old = atomicAdd(&cnt[ld >> 2], 1u << (8 * (ld & 3)));
                csr[rowstart[d] + bsumL[d >> 8] + (int)((old >> (8 * (ld & 3))) & 0xffu)] = sv;
            }
            d = clampN(d4.z);
            if (d >= nlo && d < nhi) {
                ld = d - nlo; sv = clampN(s4.z);
                old = atomicAdd(&cnt[ld >> 2], 1u << (8 * (ld & 3)));
                csr[rowstart[d] + bsumL[d >> 8] + (int)((old >> (8 * (ld & 3))) & 0xffu)] = sv;
            }
            d = clampN(d4.w);
            if (d >= nlo && d < nhi) {
                ld = d - nlo; sv = clampN(s4.w);
                old = atomicAdd(&cnt[ld >> 2], 1u << (8 * (ld & 3)));
                csr[rowstart[d] + bsumL[d >> 8] + (int)((old >> (8 * (ld & 3))) & 0xffu)] = sv;
            }
        }
    }
}

// ---------------------------------------------------------------------------
// Fused aggregate + GEMM + heads (R4-proven form). Block = 256 threads =
// 16 nodes. Phase 1: 16-lane quarter-wave per node; lane owns 4 dims
// (uint2 = 4 bf16); unroll-8 gather with software-pipelined csr index
// prefetch; bf16 mean -> LDS As[16][AGPAD].
// Phase 2: wave w computes output dims d = w*16 + (lane&15) via 4x
//   mfma_f32_16x16x32_bf16 over K=128 = [mean | x]; C/D: node = quad*4+reg,
//   d = lane&15 (R9-verified). Epilogue: relu, dual head dots, 16-lane shfl
//   reduce over d, LDS-atomic combine across the 4 waves.
// ---------------------------------------------------------------------------
__global__ __launch_bounds__(256, 8) void agg_gemm_kernel(
        const uint2* __restrict__ xb2, const short* __restrict__ xb,
        const short* __restrict__ wt,
        const int* __restrict__ rowstart, const int* __restrict__ bsum,
        const int* __restrict__ degi, const int* __restrict__ csr,
        const float* __restrict__ bl0, const float* __restrict__ Wl1,
        const float* __restrict__ Wr1,
        float* __restrict__ s, float* __restrict__ t) {
    __shared__ short As[16 * AGPAD];
    __shared__ float sRed[16], tRed[16];
    const int tid = threadIdx.x;
    const int nb = blockIdx.x * 16;          // 100000 = 6250*16, always full

    if (tid < 16) { sRed[tid] = 0.0f; tRed[tid] = 0.0f; }

    // ---- phase 1: aggregate (unroll-8, pipelined indices) ----
    {
        int qn = tid >> 4;     // node-local 0..15
        int l  = tid & 15;     // lane in quarter: dims 4l..4l+3
        int n = nb + qn;
        int beg = rowstart[n] + bsum[n >> 8];
        int cnt = degi[n];
        float4 A0 = make_float4(0.f, 0.f, 0.f, 0.f);
        float4 A1 = A0, A2 = A0, A3 = A0;
        int i = 0;
        if (cnt >= 8) {
            const int* cp = csr + beg;
            int e0 = cp[0], e1 = cp[1], e2 = cp[2], e3 = cp[3];
            int e4 = cp[4], e5 = cp[5], e6 = cp[6], e7 = cp[7];
            for (;;) {
                // 8 row-gathers in flight
                uint2 u0 = xb2[(long)e0 * 16 + l];
                uint2 u1 = xb2[(long)e1 * 16 + l];
                uint2 u2 = xb2[(long)e2 * 16 + l];
                uint2 u3 = xb2[(long)e3 * 16 + l];
                uint2 u4 = xb2[(long)e4 * 16 + l];
                uint2 u5 = xb2[(long)e5 * 16 + l];
                uint2 u6 = xb2[(long)e6 * 16 + l];
                uint2 u7 = xb2[(long)e7 * 16 + l];
                // prefetch next 8 indices while gathers are outstanding
                int ni = i + 8;
                bool more = (ni + 8 <= cnt);
                int f0, f1, f2, f3, f4, f5, f6, f7;
                if (more) {
                    const int* np = csr + beg + ni;
                    f0 = np[0]; f1 = np[1]; f2 = np[2]; f3 = np[3];
                    f4 = np[4]; f5 = np[5]; f6 = np[6]; f7 = np[7];
                }
                float2 f;
                f = upk(u0.x); A0.x += f.x; A0.y += f.y; f = upk(u0.y); A0.z += f.x; A0.w += f.y;
                f = upk(u1.x); A1.x += f.x; A1.y += f.y; f = upk(u1.y); A1.z += f.x; A1.w += f.y;
                f = upk(u2.x); A2.x += f.x; A2.y += f.y; f = upk(u2.y); A2.z += f.x; A2.w += f.y;
                f = upk(u3.x); A3.x += f.x; A3.y += f.y; f = upk(u3.y); A3.z += f.x; A3.w += f.y;
                f = upk(u4.x); A0.x += f.x; A0.y += f.y; f = upk(u4.y); A0.z += f.x; A0.w += f.y;
                f = upk(u5.x); A1.x += f.x; A1.y += f.y; f = upk(u5.y); A1.z += f.x; A1.w += f.y;
                f = upk(u6.x); A2.x += f.x; A2.y += f.y; f = upk(u6.y); A2.z += f.x; A2.w += f.y;
                f = upk(u7.x); A3.x += f.x; A3.y += f.y; f = upk(u7.y); A3.z += f.x; A3.w += f.y;
                i = ni;
                if (!more) break;
                e0 = f0; e1 = f1; e2 = f2; e3 = f3;
                e4 = f4; e5 = f5; e6 = f6; e7 = f7;
            }
        }
        if (i + 4 <= cnt) {
            int e0 = csr[beg + i],     e1 = csr[beg + i + 1];
            int e2 = csr[beg + i + 2], e3 = csr[beg + i + 3];
            uint2 u0 = xb2[(long)e0 * 16 + l];
            uint2 u1 = xb2[(long)e1 * 16 + l];
            uint2 u2 = xb2[(long)e2 * 16 + l];
            uint2 u3 = xb2[(long)e3 * 16 + l];
            float2 f;
            f = upk(u0.x); A0.x += f.x; A0.y += f.y; f = upk(u0.y); A0.z += f.x; A0.w += f.y;
            f = upk(u1.x); A1.x += f.x; A1.y += f.y; f = upk(u1.y); A1.z += f.x; A1.w += f.y;
            f = upk(u2.x); A2.x += f.x; A2.y += f.y; f = upk(u2.y); A2.z += f.x; A2.w += f.y;
            f = upk(u3.x); A3.x += f.x; A3.y += f.y; f = upk(u3.y); A3.z += f.x; A3.w += f.y;
            i += 4;
        }
        if (i < cnt) {
            uint2 u = xb2[(long)csr[beg + i] * 16 + l];
            float2 f = upk(u.x); A0.x += f.x; A0.y += f.y;
            f = upk(u.y); A0.z += f.x; A0.w += f.y;
        }
        if (i + 1 < cnt) {
            uint2 u = xb2[(long)csr[beg + i + 1] * 16 + l];
            float2 f = upk(u.x); A1.x += f.x; A1.y += f.y;
            f = upk(u.y); A1.z += f.x; A1.w += f.y;
        }
        if (i + 2 < cnt) {
            uint2 u = xb2[(long)csr[beg + i + 2] * 16 + l];
            float2 f = upk(u.x); A2.x += f.x; A2.y += f.y;
            f = upk(u.y); A2.z += f.x; A2.w += f.y;
        }
        float inv = 1.0f / fmaxf((float)cnt, 1.0f);
        float ax = (A0.x + A1.x + A2.x + A3.x) * inv;
        float ay = (A0.y + A1.y + A2.y + A3.y) * inv;
        float az = (A0.z + A1.z + A2.z + A3.z) * inv;
        float aw = (A0.w + A1.w + A2.w + A3.w) * inv;
        *(uint2*)&As[qn * AGPAD + 4 * l] =
            make_uint2(packbf2(ax, ay), packbf2(az, aw));
    }
    __syncthreads();

    // ---- phase 2: MFMA + heads ----
    const int lane = tid & 63;
    const int w = tid >> 6;
    const int r = lane & 15;
    const int quad = lane >> 4;

    short8 a0 = *(const short8*)&As[r * AGPAD + quad * 8];        // k  0..31
    short8 a1 = *(const short8*)&As[r * AGPAD + 32 + quad * 8];   // k 32..63
    const long xrow = (long)(nb + r) * 64 + quad * 8;
    short8 a2 = *(const short8*)(xb + xrow);                      // k 64..95
    short8 a3 = *(const short8*)(xb + xrow + 32);                 // k 96..127

    const int d = w * 16 + r;
    const short* brow = wt + (long)d * 128 + quad * 8;
    short8 b0 = *(const short8*)(brow);
    short8 b1 = *(const short8*)(brow + 32);
    short8 b2 = *(const short8*)(brow + 64);
    short8 b3 = *(const short8*)(brow + 96);

    float bb = bl0[d];
    floatx4 acc = {bb, bb, bb, bb};
    acc = __builtin_amdgcn_mfma_f32_16x16x32_bf16(a0, b0, acc, 0, 0, 0);
    acc = __builtin_amdgcn_mfma_f32_16x16x32_bf16(a1, b1, acc, 0, 0, 0);
    acc = __builtin_amdgcn_mfma_f32_16x16x32_bf16(a2, b2, acc, 0, 0, 0);
    acc = __builtin_amdgcn_mfma_f32_16x16x32_bf16(a3, b3, acc, 0, 0, 0);

    float w1 = Wl1[d], w2 = Wr1[d];
    float hs[4], ht[4];
    #pragma unroll
    for (int g = 0; g < 4; ++g) {
        float h = fmaxf(acc[g], 0.0f);
        hs[g] = h * w1;
        ht[g] = h * w2;
    }
    #pragma unroll
    for (int g = 0; g < 4; ++g) {
        #pragma unroll
        for (int off = 1; off < 16; off <<= 1) {
            hs[g] += __shfl_xor(hs[g], off, 64);
            ht[g] += __shfl_xor(ht[g], off, 64);
        }
    }
    if (r == 0) {
        #pragma unroll
        for (int g = 0; g < 4; ++g) {
            atomicAdd(&sRed[quad * 4 + g], hs[g]);
            atomicAdd(&tRed[quad * 4 + g], ht[g]);
        }
    }
    __syncthreads();
    if (tid < 16) {
        s[nb + tid] = sRed[tid];
        t[nb + tid] = tRed[tid];
    }
}

// ---------------------------------------------------------------------------
// Final: CSR-gather of s (8-wide ILP), mean, + bl1 + t, sigmoid, fp32 out.
// ---------------------------------------------------------------------------
__global__ void final_kernel(const float* __restrict__ s,
                             const float* __restrict__ t,
                             const int* __restrict__ rowstart,
                             const int* __restrict__ bsum,
                             const int* __restrict__ degi,
                             const int* __restrict__ csr,
                             const float* __restrict__ bl1,
                             float* __restrict__ out) {
    int n = blockIdx.x * 256 + threadIdx.x;
    if (n >= N_NODES) return;
    int beg = rowstart[n] + bsum[n >> 8];
    int cnt = degi[n];
    float acc = 0.0f;
    int i = 0;
    for (; i + 8 <= cnt; i += 8) {
        int e0 = csr[beg + i],     e1 = csr[beg + i + 1];
        int e2 = csr[beg + i + 2], e3 = csr[beg + i + 3];
        int e4 = csr[beg + i + 4], e5 = csr[beg + i + 5];
        int e6 = csr[beg + i + 6], e7 = csr[beg + i + 7];
        float v0 = s[e0], v1 = s[e1], v2 = s[e2], v3 = s[e3];
        float v4 = s[e4], v5 = s[e5], v6 = s[e6], v7 = s[e7];
        acc += ((v0 + v1) + (v2 + v3)) + ((v4 + v5) + (v6 + v7));
    }
    for (; i + 4 <= cnt; i += 4) {
        int e0 = csr[beg + i], e1 = csr[beg + i + 1];
        int e2 = csr[beg + i + 2], e3 = csr[beg + i + 3];
        acc += s[e0] + s[e1] + s[e2] + s[e3];
    }
    for (; i < cnt; ++i) acc += s[csr[beg + i]];
    float v = acc / fmaxf((float)cnt, 1.0f) + bl1[0] + t[n];
    float sg = 1.0f / (1.0f + expf(-v));
    out[n] = v;
    out[N_NODES + n] = sg;
}

extern "C" void kernel_launch(void* const* d_in, const int* in_sizes, int n_in,
                              void* d_out, int out_size, void* d_ws, size_t ws_size,
                              hipStream_t stream) {
    const float* x   = (const float*)d_in[0];
    const int*   ei  = (const int*)d_in[1];   // int32, [2,E] flat: src row, dst row
    const float* Wl0 = (const float*)d_in[2];
    const float* bl0 = (const float*)d_in[3];
    const float* Wr0 = (const float*)d_in[4];
    const float* Wl1 = (const float*)d_in[5];
    const float* bl1 = (const float*)d_in[6];
    const float* Wr1 = (const float*)d_in[7];
    float* out = (float*)d_out;

    // Workspace layout (~30.9 MB, all offsets 16-B aligned):
    //   degi     @0            (400,000)    written by build (totals)
    //   rowstart @400,000      (400,000)
    //   bsum     @800,000      (2,048)      chunk bases (agg/final)
    //   chsum    @802,048      (2,048)      raw chunk sums (build-internal)
    //   s        @804,096      (400,000)
    //   t        @1,204,096    (400,000)
    //   csr      @1,604,096    (4,000,000)
    //   xb       @5,604,096    (12,800,000)  bf16 x rows
    //   wt       @18,404,096   (16,384)      bf16 [Wl0|Wr0] rows
    //   bh       @18,420,480   (12,500,000)  125 per-segment byte histograms
    char* ws = (char*)d_ws;
    int*   degi     = (int*)(ws);
    int*   rowstart = (int*)(ws + 400000);
    int*   bsum     = (int*)(ws + 800000);
    int*   chsum    = (int*)(ws + 802048);
    float* s        = (float*)(ws + 804096);
    float* t        = (float*)(ws + 1204096);
    int*   csr      = (int*)(ws + 1604096);
    char*  xb       = (ws + 5604096);
    short* wt       = (short*)(ws + 18404096);
    char*  bh       = (ws + 18420480);

    unsigned int* bh32 = (unsigned int*)bh;
    const float4* x4 = (const float4*)x;
    uint2* xb4 = (uint2*)xb;
    void* args[] = { (void*)&ei, (void*)&bh32, (void*)&x4, (void*)&xb4,
                     (void*)&Wl0, (void*)&Wr0, (void*)&wt, (void*)&degi,
                     (void*)&rowstart, (void*)&chsum, (void*)&bsum, (void*)&csr };
    (void)hipLaunchCooperativeKernel((const void*)build_kernel,
                                     dim3(BBLOCKS), dim3(BTHREADS),
                                     args, 0, stream);
    agg_gemm_kernel<<<6250, 256, 0, stream>>>((const uint2*)xb, (const short*)xb,
                                              wt, rowstart, bsum, degi, csr,
                                              bl0, Wl1, Wr1, s, t);
    final_kernel<<<NCHUNK, 256, 0, stream>>>(s, t, rowstart, bsum, degi, csr,
                                             bl1, out);
}

// Round 8
// 235.074 us; speedup vs baseline: 1.1044x; 1.1044x over previous
//
#include <hip/hip_runtime.h>
#include <hip/hip_bf16.h>
#include <math.h>

#define N_NODES 100000
#define N_EDGES 1000000
#define DIM 64
#define SCAN_BLOCKS 391   // ceil(N_NODES/256)
#define AGPAD 72          // LDS row stride in shorts (16-B aligned, conflict-light)
#define NHB 125           // histogram segments (LDS-private byte histograms)
#define HTHREADS 1024     // threads per count/fill block (16 waves: latency hiding)
#define EPB (N_EDGES / NHB)         // 8000 edges per histogram segment
#define HWORDS ((N_NODES + 3) / 4)  // 25000 packed words per histogram
#define HALF_NODES (N_NODES / 2)    // 50000: node-range split for count/fill
#define HWORDS_HALF (HALF_NODES / 4) // 12500 words = 50KB LDS per block
#define NUNITS 6250       // 16-node work units for agg (100000/16)
#define AGG_BLOCKS 2048   // persistent agg blocks (8 per CU)

// Device dtypes (established empirically R1-R8): fp32 floats, int32 indices,
// fp32 output.
typedef __hip_bfloat16 bf16;
typedef __attribute__((ext_vector_type(8))) short short8;
typedef __attribute__((ext_vector_type(4))) float floatx4;

__device__ __forceinline__ float b2f(bf16 v) { return __bfloat162float(v); }

__device__ __forceinline__ unsigned int packbf2(float a, float b) {
    bf16 x = __float2bfloat16(a), y = __float2bfloat16(b);
    unsigned short ux = *(unsigned short*)&x, uy = *(unsigned short*)&y;
    return (unsigned int)ux | ((unsigned int)uy << 16);
}

__device__ __forceinline__ short f2bs(float v) {
    bf16 x = __float2bfloat16(v);
    return *(short*)&x;
}

__device__ __forceinline__ float2 upk(unsigned int u) {
    unsigned short lo = (unsigned short)(u & 0xffff);
    unsigned short hi = (unsigned short)(u >> 16);
    bf16 a = *(bf16*)&lo, b = *(bf16*)&hi;
    return make_float2(b2f(a), b2f(b));
}

__device__ __forceinline__ int clampN(int v) {
    return v < 0 ? 0 : (v >= N_NODES ? N_NODES - 1 : v);
}

// ---------------------------------------------------------------------------
// CSR build: LDS byte-counter histograms, R6-proven form (R7's cooperative
// fusion REVERTED: grid.sync's device-scope fences across non-coherent XCD
// L2s destroyed the L2-warm producer->consumer flow; 108us vs 35us split).
// Each segment handled by TWO blocks, each owning half the node range
// (50KB LDS). Degrees per 8000-edge segment max ~5 << 255 so byte counters
// can't overflow. Zero global atomics in the build.
// ---------------------------------------------------------------------------

// count: per-(segment,half) LDS byte histogram of dst, dumped to bh.
__global__ __launch_bounds__(HTHREADS) void count_kernel(const int* __restrict__ ei,
                                                         unsigned int* __restrict__ bh32) {
    __shared__ unsigned int cnt[HWORDS_HALF];
    const int t = threadIdx.x;
    const int seg = blockIdx.x >> 1, half = blockIdx.x & 1;
    const int nlo = half * HALF_NODES, nhi = nlo + HALF_NODES;
    for (int w = t; w < HWORDS_HALF; w += HTHREADS) cnt[w] = 0u;
    __syncthreads();
    const int4* dst4 = (const int4*)(ei + N_EDGES + seg * EPB);
    for (int k = t; k < EPB / 4; k += HTHREADS) {
        int4 d4 = dst4[k];
        int d;
        d = clampN(d4.x); if (d >= nlo && d < nhi) { int ld = d - nlo; atomicAdd(&cnt[ld >> 2], 1u << (8 * (ld & 3))); }
        d = clampN(d4.y); if (d >= nlo && d < nhi) { int ld = d - nlo; atomicAdd(&cnt[ld >> 2], 1u << (8 * (ld & 3))); }
        d = clampN(d4.z); if (d >= nlo && d < nhi) { int ld = d - nlo; atomicAdd(&cnt[ld >> 2], 1u << (8 * (ld & 3))); }
        d = clampN(d4.w); if (d >= nlo && d < nhi) { int ld = d - nlo; atomicAdd(&cnt[ld >> 2], 1u << (8 * (ld & 3))); }
    }
    __syncthreads();
    unsigned int* out = bh32 + (long)seg * HWORDS + half * HWORDS_HALF;
    for (int w = t; w < HWORDS_HALF; w += HTHREADS) out[w] = cnt[w];
}

// scan1 + convert fused (disjoint block ranges; scan1 uses only ~1.3KB LDS so
// convert occupancy is unharmed). convert depends on nothing and would
// otherwise serialize on the stream; it rides alongside scan1.
__global__ void scan1_convert_kernel(unsigned char* __restrict__ bhb,
                                     int* __restrict__ degi,
                                     int* __restrict__ rowstart,
                                     int* __restrict__ bsum,
                                     const float4* __restrict__ x4,
                                     uint2* __restrict__ xb4,
                                     const float* __restrict__ Wl0,
                                     const float* __restrict__ Wr0,
                                     short* __restrict__ wt) {
    __shared__ int sc[256];
    int b = blockIdx.x;
    int t = threadIdx.x;
    if (b >= SCAN_BLOCKS) {
        int bb = b - SCAN_BLOCKS;
        if (bb < 6250) {
            int idx = bb * 256 + t;            // < 1,600,000 exactly
            float4 f = x4[idx];
            xb4[idx] = make_uint2(packbf2(f.x, f.y), packbf2(f.z, f.w));
        } else {
            for (int i = t; i < 8192; i += 256) {
                int d = i >> 7, k = i & 127;
                float v = (k < 64) ? Wl0[d * 64 + k] : Wr0[d * 64 + (k - 64)];
                wt[i] = f2bs(v);
            }
        }
        return;
    }
    int i = b * 256 + t;
    int v = 0;
    if (i < N_NODES) {
        int sum = 0;
        #pragma unroll 5
        for (int c = 0; c < NHB; ++c) {
            long off = (long)c * (HWORDS * 4) + i;
            int u = bhb[off];
            bhb[off] = (unsigned char)sum;   // exclusive base for segment c
            sum += u;
        }
        degi[i] = sum;                       // total degree
        v = sum;
    }
    sc[t] = v;
    __syncthreads();
    #pragma unroll
    for (int off = 1; off < 256; off <<= 1) {
        int u = (t >= off) ? sc[t - off] : 0;
        __syncthreads();
        sc[t] += u;
        __syncthreads();
    }
    if (i < N_NODES) rowstart[i] = sc[t] - v;   // exclusive within block
    if (t == 255) bsum[b] = sc[t];
}

__global__ void scan2_kernel(int* __restrict__ bsum) {
    __shared__ int sc[512];
    int t = threadIdx.x;
    int v = (t < SCAN_BLOCKS) ? bsum[t] : 0;
    sc[t] = v;
    __syncthreads();
    #pragma unroll
    for (int off = 1; off < 512; off <<= 1) {
        int u = (t >= off) ? sc[t - off] : 0;
        __syncthreads();
        sc[t] += u;
        __syncthreads();
    }
    if (t < SCAN_BLOCKS) bsum[t] = sc[t] - v;   // exclusive
}

// fill: per-(segment,half) reload bases into LDS as counter INITIAL values;
// ds_add_rtn per in-range edge yields base+rank directly. Pure LDS atomics,
// global scatter only for the final csr write.
__global__ __launch_bounds__(HTHREADS) void fill_kernel(const int* __restrict__ ei,
                                                        const int* __restrict__ rowstart,
                                                        const int* __restrict__ bsum,
                                                        const unsigned int* __restrict__ bh32,
                                                        int* __restrict__ csr) {
    __shared__ unsigned int cnt[HWORDS_HALF];
    const int t = threadIdx.x;
    const int seg = blockIdx.x >> 1, half = blockIdx.x & 1;
    const int nlo = half * HALF_NODES, nhi = nlo + HALF_NODES;
    const unsigned int* in = bh32 + (long)seg * HWORDS + half * HWORDS_HALF;
    for (int w = t; w < HWORDS_HALF; w += HTHREADS) cnt[w] = in[w];
    __syncthreads();
    const int4* srcp4 = (const int4*)(ei + seg * EPB);
    const int4* dstp4 = (const int4*)(ei + N_EDGES + seg * EPB);
    for (int k = t; k < EPB / 4; k += HTHREADS) {
        int4 s4 = srcp4[k];
        int4 d4 = dstp4[k];
        int d, ld, sv;
        unsigned int old;
        d = clampN(d4.x);
        if (d >= nlo && d < nhi) {
            ld = d - nlo; sv = clampN(s4.x);
            old = atomicAdd(&cnt[ld >> 2], 1u << (8 * (ld & 3)));
            csr[rowstart[d] + bsum[d >> 8] + (int)((old >> (8 * (ld & 3))) & 0xffu)] = sv;
        }
        d = clampN(d4.y);
        if (d >= nlo && d < nhi) {
            ld = d - nlo; sv = clampN(s4.y);
            old = atomicAdd(&cnt[ld >> 2], 1u << (8 * (ld & 3)));
            csr[rowstart[d] + bsum[d >> 8] + (int)((old >> (8 * (ld & 3))) & 0xffu)] = sv;
        }
        d = clampN(d4.z);
        if (d >= nlo && d < nhi) {
            ld = d - nlo; sv = clampN(s4.z);
            old = atomicAdd(&cnt[ld >> 2], 1u << (8 * (ld & 3)));
            csr[rowstart[d] + bsum[d >> 8] + (int)((old >> (8 * (ld & 3))) & 0xffu)] = sv;
        }
        d = clampN(d4.w);
        if (d >= nlo && d < nhi) {
            ld = d - nlo; sv = clampN(s4.w);
            old = atomicAdd(&cnt[ld >> 2], 1u << (8 * (ld & 3)));
            csr[rowstart[d] + bsum[d >> 8] + (int)((old >> (8 * (ld & 3))) & 0xffu)] = sv;
        }
    }
}

// ---------------------------------------------------------------------------
// Fused aggregate + GEMM + heads (R4-proven inner code). R8: persistent
// blocks + atomic work-stealing. agg's 56.6% time-avg occupancy with trivial
// resource limits = drain-phase stragglers (static block->unit map; per-block
// edge totals vary, max of 6250 ~ +35% over mean). 2048 blocks (8/CU) each
// grab contiguous 16-node units off a global counter: inner code identical,
// writes stay coalesced (R5 lesson), 6250 global atomics total (trivial vs
// the 20 G/s cap measured in R1).
// ---------------------------------------------------------------------------
__global__ __launch_bounds__(256) void agg_gemm_kernel(
        const uint2* __restrict__ xb2, const short* __restrict__ xb,
        const short* __restrict__ wt,
        const int* __restrict__ rowstart, const int* __restrict__ bsum,
        const int* __restrict__ degi, const int* __restrict__ csr,
        const float* __restrict__ bl0, const float* __restrict__ Wl1,
        const float* __restrict__ Wr1,
        int* __restrict__ ctr,
        float* __restrict__ s, float* __restrict__ t) {
    __shared__ short As[16 * AGPAD];
    __shared__ float sRed[16], tRed[16];
    __shared__ int unitS;
    const int tid = threadIdx.x;

    for (;;) {
        if (tid == 0) unitS = atomicAdd(ctr, 1);
        __syncthreads();                       // unitS visible; prev unit drained
        const int unit = unitS;
        if (unit >= NUNITS) return;
        const int nb = unit * 16;
        if (tid < 16) { sRed[tid] = 0.0f; tRed[tid] = 0.0f; }

        // ---- phase 1: aggregate (unroll-8, pipelined indices) ----
        {
            int qn = tid >> 4;     // node-local 0..15
            int l  = tid & 15;     // lane in quarter: dims 4l..4l+3
            int n = nb + qn;
            int beg = rowstart[n] + bsum[n >> 8];
            int cnt = degi[n];
            float4 A0 = make_float4(0.f, 0.f, 0.f, 0.f);
            float4 A1 = A0, A2 = A0, A3 = A0;
            int i = 0;
            if (cnt >= 8) {
                const int* cp = csr + beg;
                int e0 = cp[0], e1 = cp[1], e2 = cp[2], e3 = cp[3];
                int e4 = cp[4], e5 = cp[5], e6 = cp[6], e7 = cp[7];
                for (;;) {
                    // 8 row-gathers in flight
                    uint2 u0 = xb2[(long)e0 * 16 + l];
                    uint2 u1 = xb2[(long)e1 * 16 + l];
                    uint2 u2 = xb2[(long)e2 * 16 + l];
                    uint2 u3 = xb2[(long)e3 * 16 + l];
                    uint2 u4 = xb2[(long)e4 * 16 + l];
                    uint2 u5 = xb2[(long)e5 * 16 + l];
                    uint2 u6 = xb2[(long)e6 * 16 + l];
                    uint2 u7 = xb2[(long)e7 * 16 + l];
                    // prefetch next 8 indices while gathers are outstanding
                    int ni = i + 8;
                    bool more = (ni + 8 <= cnt);
                    int f0, f1, f2, f3, f4, f5, f6, f7;
                    if (more) {
                        const int* np = csr + beg + ni;
                        f0 = np[0]; f1 = np[1]; f2 = np[2]; f3 = np[3];
                        f4 = np[4]; f5 = np[5]; f6 = np[6]; f7 = np[7];
                    }
                    float2 f;
                    f = upk(u0.x); A0.x += f.x; A0.y += f.y; f = upk(u0.y); A0.z += f.x; A0.w += f.y;
                    f = upk(u1.x); A1.x += f.x; A1.y += f.y; f = upk(u1.y); A1.z += f.x; A1.w += f.y;
                    f = upk(u2.x); A2.x += f.x; A2.y += f.y; f = upk(u2.y); A2.z += f.x; A2.w += f.y;
                    f = upk(u3.x); A3.x += f.x; A3.y += f.y; f = upk(u3.y); A3.z += f.x; A3.w += f.y;
                    f = upk(u4.x); A0.x += f.x; A0.y += f.y; f = upk(u4.y); A0.z += f.x; A0.w += f.y;
                    f = upk(u5.x); A1.x += f.x; A1.y += f.y; f = upk(u5.y); A1.z += f.x; A1.w += f.y;
                    f = upk(u6.x); A2.x += f.x; A2.y += f.y; f = upk(u6.y); A2.z += f.x; A2.w += f.y;
                    f = upk(u7.x); A3.x += f.x; A3.y += f.y; f = upk(u7.y); A3.z += f.x; A3.w += f.y;
                    i = ni;
                    if (!more) break;
                    e0 = f0; e1 = f1; e2 = f2; e3 = f3;
                    e4 = f4; e5 = f5; e6 = f6; e7 = f7;
                }
            }
            if (i + 4 <= cnt) {
                int e0 = csr[beg + i],     e1 = csr[beg + i + 1];
                int e2 = csr[beg + i + 2], e3 = csr[beg + i + 3];
                uint2 u0 = xb2[(long)e0 * 16 + l];
                uint2 u1 = xb2[(long)e1 * 16 + l];
                uint2 u2 = xb2[(long)e2 * 16 + l];
                uint2 u3 = xb2[(long)e3 * 16 + l];
                float2 f;
                f = upk(u0.x); A0.x += f.x; A0.y += f.y; f = upk(u0.y); A0.z += f.x; A0.w += f.y;
                f = upk(u1.x); A1.x += f.x; A1.y += f.y; f = upk(u1.y); A1.z += f.x; A1.w += f.y;
                f = upk(u2.x); A2.x += f.x; A2.y += f.y; f = upk(u2.y); A2.z += f.x; A2.w += f.y;
                f = upk(u3.x); A3.x += f.x; A3.y += f.y; f = upk(u3.y); A3.z += f.x; A3.w += f.y;
                i += 4;
            }
            if (i < cnt) {
                uint2 u = xb2[(long)csr[beg + i] * 16 + l];
                float2 f = upk(u.x); A0.x += f.x; A0.y += f.y;
                f = upk(u.y); A0.z += f.x; A0.w += f.y;
            }
            if (i + 1 < cnt) {
                uint2 u = xb2[(long)csr[beg + i + 1] * 16 + l];
                float2 f = upk(u.x); A1.x += f.x; A1.y += f.y;
                f = upk(u.y); A1.z += f.x; A1.w += f.y;
            }
            if (i + 2 < cnt) {
                uint2 u = xb2[(long)csr[beg + i + 2] * 16 + l];
                float2 f = upk(u.x); A2.x += f.x; A2.y += f.y;
                f = upk(u.y); A2.z += f.x; A2.w += f.y;
            }
            float inv = 1.0f / fmaxf((float)cnt, 1.0f);
            float ax = (A0.x + A1.x + A2.x + A3.x) * inv;
            float ay = (A0.y + A1.y + A2.y + A3.y) * inv;
            float az = (A0.z + A1.z + A2.z + A3.z) * inv;
            float aw = (A0.w + A1.w + A2.w + A3.w) * inv;
            *(uint2*)&As[qn * AGPAD + 4 * l] =
                make_uint2(packbf2(ax, ay), packbf2(az, aw));
        }
        __syncthreads();

        // ---- phase 2: MFMA + heads ----
        {
            const int lane = tid & 63;
            const int w = tid >> 6;
            const int r = lane & 15;
            const int quad = lane >> 4;

            short8 a0 = *(const short8*)&As[r * AGPAD + quad * 8];        // k  0..31
            short8 a1 = *(const short8*)&As[r * AGPAD + 32 + quad * 8];   // k 32..63
            const long xrow = (long)(nb + r) * 64 + quad * 8;
            short8 a2 = *(const short8*)(xb + xrow);                      // k 64..95
            short8 a3 = *(const short8*)(xb + xrow + 32);                 // k 96..127

            const int d = w * 16 + r;
            const short* brow = wt + (long)d * 128 + quad * 8;
            short8 b0 = *(const short8*)(brow);
            short8 b1 = *(const short8*)(brow + 32);
            short8 b2 = *(const short8*)(brow + 64);
            short8 b3 = *(const short8*)(brow + 96);

            float bb = bl0[d];
            floatx4 acc = {bb, bb, bb, bb};
            acc = __builtin_amdgcn_mfma_f32_16x16x32_bf16(a0, b0, acc, 0, 0, 0);
            acc = __builtin_amdgcn_mfma_f32_16x16x32_bf16(a1, b1, acc, 0, 0, 0);
            acc = __builtin_amdgcn_mfma_f32_16x16x32_bf16(a2, b2, acc, 0, 0, 0);
            acc = __builtin_amdgcn_mfma_f32_16x16x32_bf16(a3, b3, acc, 0, 0, 0);

            float w1 = Wl1[d], w2 = Wr1[d];
            float hs[4], ht[4];
            #pragma unroll
            for (int g = 0; g < 4; ++g) {
                float h = fmaxf(acc[g], 0.0f);
                hs[g] = h * w1;
                ht[g] = h * w2;
            }
            #pragma unroll
            for (int g = 0; g < 4; ++g) {
                #pragma unroll
                for (int off = 1; off < 16; off <<= 1) {
                    hs[g] += __shfl_xor(hs[g], off, 64);
                    ht[g] += __shfl_xor(ht[g], off, 64);
                }
            }
            if (r == 0) {
                #pragma unroll
                for (int g = 0; g < 4; ++g) {
                    atomicAdd(&sRed[quad * 4 + g], hs[g]);
                    atomicAdd(&tRed[quad * 4 + g], ht[g]);
                }
            }
        }
        __syncthreads();
        if (tid < 16) {
            s[nb + tid] = sRed[tid];
            t[nb + tid] = tRed[tid];
        }
    }
}

// ---------------------------------------------------------------------------
// Final: CSR-gather of s (8-wide ILP), mean, + bl1 + t, sigmoid, fp32 out.
// ---------------------------------------------------------------------------
__global__ void final_kernel(const float* __restrict__ s,
                             const float* __restrict__ t,
                             const int* __restrict__ rowstart,
                             const int* __restrict__ bsum,
                             const int* __restrict__ degi,
                             const int* __restrict__ csr,
                             const float* __restrict__ bl1,
                             float* __restrict__ out) {
    int n = blockIdx.x * 256 + threadIdx.x;
    if (n >= N_NODES) return;
    int beg = rowstart[n] + bsum[n >> 8];
    int cnt = degi[n];
    float acc = 0.0f;
    int i = 0;
    for (; i + 8 <= cnt; i += 8) {
        int e0 = csr[beg + i],     e1 = csr[beg + i + 1];
        int e2 = csr[beg + i + 2], e3 = csr[beg + i + 3];
        int e4 = csr[beg + i + 4], e5 = csr[beg + i + 5];
        int e6 = csr[beg + i + 6], e7 = csr[beg + i + 7];
        float v0 = s[e0], v1 = s[e1], v2 = s[e2], v3 = s[e3];
        float v4 = s[e4], v5 = s[e5], v6 = s[e6], v7 = s[e7];
        acc += ((v0 + v1) + (v2 + v3)) + ((v4 + v5) + (v6 + v7));
    }
    for (; i + 4 <= cnt; i += 4) {
        int e0 = csr[beg + i], e1 = csr[beg + i + 1];
        int e2 = csr[beg + i + 2], e3 = csr[beg + i + 3];
        acc += s[e0] + s[e1] + s[e2] + s[e3];
    }
    for (; i < cnt; ++i) acc += s[csr[beg + i]];
    float v = acc / fmaxf((float)cnt, 1.0f) + bl1[0] + t[n];
    float sg = 1.0f / (1.0f + expf(-v));
    out[n] = v;
    out[N_NODES + n] = sg;
}

extern "C" void kernel_launch(void* const* d_in, const int* in_sizes, int n_in,
                              void* d_out, int out_size, void* d_ws, size_t ws_size,
                              hipStream_t stream) {
    const float* x   = (const float*)d_in[0];
    const int*   ei  = (const int*)d_in[1];   // int32, [2,E] flat: src row, dst row
    const float* Wl0 = (const float*)d_in[2];
    const float* bl0 = (const float*)d_in[3];
    const float* Wr0 = (const float*)d_in[4];
    const float* Wl1 = (const float*)d_in[5];
    const float* bl1 = (const float*)d_in[6];
    const float* Wr1 = (const float*)d_in[7];
    float* out = (float*)d_out;

    // Workspace layout (~30.9 MB, all offsets 16-B aligned):
    //   degi     @0            (400,000)    written by scan1 (totals)
    //   rowstart @400,000      (400,000)
    //   bsum     @800,000      (4,096)
    //   s        @804,096      (400,000)
    //   t        @1,204,096    (400,000)
    //   csr      @1,604,096    (4,000,000)
    //   xb       @5,604,096    (12,800,000)  bf16 x rows
    //   wt       @18,404,096   (16,384)      bf16 [Wl0|Wr0] rows
    //   bh       @18,420,480   (12,500,000)  125 per-segment byte histograms
    //   ctr      @30,920,480   (16)          agg work-stealing counter
    char* ws = (char*)d_ws;
    int*   degi     = (int*)(ws);
    int*   rowstart = (int*)(ws + 400000);
    int*   bsum     = (int*)(ws + 800000);
    float* s        = (float*)(ws + 804096);
    float* t        = (float*)(ws + 1204096);
    int*   csr      = (int*)(ws + 1604096);
    char*  xb       = (ws + 5604096);
    short* wt       = (short*)(ws + 18404096);
    char*  bh       = (ws + 18420480);
    int*   ctr      = (int*)(ws + 30920480);

    (void)hipMemsetAsync(ctr, 0, 16, stream);

    count_kernel<<<2 * NHB, HTHREADS, 0, stream>>>(ei, (unsigned int*)bh);
    scan1_convert_kernel<<<SCAN_BLOCKS + 6251, 256, 0, stream>>>(
        (unsigned char*)bh, degi, rowstart, bsum,
        (const float4*)x, (uint2*)xb, Wl0, Wr0, wt);
    scan2_kernel<<<1, 512, 0, stream>>>(bsum);
    fill_kernel<<<2 * NHB, HTHREADS, 0, stream>>>(ei, rowstart, bsum,
                                                  (const unsigned int*)bh, csr);
    agg_gemm_kernel<<<AGG_BLOCKS, 256, 0, stream>>>((const uint2*)xb, (const short*)xb,
                                                    wt, rowstart, bsum, degi, csr,
                                                    bl0, Wl1, Wr1, ctr, s, t);
    final_kernel<<<SCAN_BLOCKS, 256, 0, stream>>>(s, t, rowstart, bsum, degi, csr,
                                                  bl1, out);
}

// Round 9
// 170.384 us; speedup vs baseline: 1.5237x; 1.3797x over previous
//
#include <hip/hip_runtime.h>
#include <hip/hip_bf16.h>
#include <math.h>

#define N_NODES 100000
#define N_EDGES 1000000
#define DIM 64
#define SCAN_BLOCKS 391   // ceil(N_NODES/256)
#define AGPAD 72          // LDS row stride in shorts (16-B aligned, conflict-light)
#define NHB 125           // histogram segments (LDS-private byte histograms)
#define HTHREADS 1024     // threads per count/fill block (16 waves: latency hiding)
#define EPB (N_EDGES / NHB)         // 8000 edges per histogram segment
#define HWORDS ((N_NODES + 3) / 4)  // 25000 packed words per histogram
#define HALF_NODES (N_NODES / 2)    // 50000: node-range split for count/fill
#define HWORDS_HALF (HALF_NODES / 4) // 12500 words = 50KB LDS per block

// Device dtypes (established empirically R1-R8): fp32 floats, int32 indices,
// fp32 output.
typedef __hip_bfloat16 bf16;
typedef __attribute__((ext_vector_type(8))) short short8;
typedef __attribute__((ext_vector_type(4))) float floatx4;

__device__ __forceinline__ float b2f(bf16 v) { return __bfloat162float(v); }

__device__ __forceinline__ unsigned int packbf2(float a, float b) {
    bf16 x = __float2bfloat16(a), y = __float2bfloat16(b);
    unsigned short ux = *(unsigned short*)&x, uy = *(unsigned short*)&y;
    return (unsigned int)ux | ((unsigned int)uy << 16);
}

__device__ __forceinline__ short f2bs(float v) {
    bf16 x = __float2bfloat16(v);
    return *(short*)&x;
}

__device__ __forceinline__ float2 upk(unsigned int u) {
    unsigned short lo = (unsigned short)(u & 0xffff);
    unsigned short hi = (unsigned short)(u >> 16);
    bf16 a = *(bf16*)&lo, b = *(bf16*)&hi;
    return make_float2(b2f(a), b2f(b));
}

__device__ __forceinline__ int clampN(int v) {
    return v < 0 ? 0 : (v >= N_NODES ? N_NODES - 1 : v);
}

// ---------------------------------------------------------------------------
// CSR build: LDS byte-counter histograms, R6-proven form. R8's global
// work-stealing counter REVERTED (6250 same-address atomics serialized at
// ~60M/s cross-XCD = 104us; the HW dispatcher already load-balances static
// blocks). R9: scan2 folded into fill's prologue (each fill block redundantly
// scans the 391 raw chunk sums in LDS; block 0 persists exclusive bsum for
// agg/final) — one dispatch + stream gap removed, no cross-kernel coherence
// tricks (R7 lesson).
// ---------------------------------------------------------------------------

// count: per-(segment,half) LDS byte histogram of dst, dumped to bh.
__global__ __launch_bounds__(HTHREADS) void count_kernel(const int* __restrict__ ei,
                                                         unsigned int* __restrict__ bh32) {
    __shared__ unsigned int cnt[HWORDS_HALF];
    const int t = threadIdx.x;
    const int seg = blockIdx.x >> 1, half = blockIdx.x & 1;
    const int nlo = half * HALF_NODES, nhi = nlo + HALF_NODES;
    for (int w = t; w < HWORDS_HALF; w += HTHREADS) cnt[w] = 0u;
    __syncthreads();
    const int4* dst4 = (const int4*)(ei + N_EDGES + seg * EPB);
    for (int k = t; k < EPB / 4; k += HTHREADS) {
        int4 d4 = dst4[k];
        int d;
        d = clampN(d4.x); if (d >= nlo && d < nhi) { int ld = d - nlo; atomicAdd(&cnt[ld >> 2], 1u << (8 * (ld & 3))); }
        d = clampN(d4.y); if (d >= nlo && d < nhi) { int ld = d - nlo; atomicAdd(&cnt[ld >> 2], 1u << (8 * (ld & 3))); }
        d = clampN(d4.z); if (d >= nlo && d < nhi) { int ld = d - nlo; atomicAdd(&cnt[ld >> 2], 1u << (8 * (ld & 3))); }
        d = clampN(d4.w); if (d >= nlo && d < nhi) { int ld = d - nlo; atomicAdd(&cnt[ld >> 2], 1u << (8 * (ld & 3))); }
    }
    __syncthreads();
    unsigned int* out = bh32 + (long)seg * HWORDS + half * HWORDS_HALF;
    for (int w = t; w < HWORDS_HALF; w += HTHREADS) out[w] = cnt[w];
}

// scan1 + convert fused (disjoint block ranges; scan1 uses only ~1.3KB LDS so
// convert occupancy is unharmed). Writes RAW chunk sums to chsum (fill scans
// them). convert depends on nothing and rides alongside scan1.
__global__ void scan1_convert_kernel(unsigned char* __restrict__ bhb,
                                     int* __restrict__ degi,
                                     int* __restrict__ rowstart,
                                     int* __restrict__ chsum,
                                     const float4* __restrict__ x4,
                                     uint2* __restrict__ xb4,
                                     const float* __restrict__ Wl0,
                                     const float* __restrict__ Wr0,
                                     short* __restrict__ wt) {
    __shared__ int sc[256];
    int b = blockIdx.x;
    int t = threadIdx.x;
    if (b >= SCAN_BLOCKS) {
        int bb = b - SCAN_BLOCKS;
        if (bb < 6250) {
            int idx = bb * 256 + t;            // < 1,600,000 exactly
            float4 f = x4[idx];
            xb4[idx] = make_uint2(packbf2(f.x, f.y), packbf2(f.z, f.w));
        } else {
            for (int i = t; i < 8192; i += 256) {
                int d = i >> 7, k = i & 127;
                float v = (k < 64) ? Wl0[d * 64 + k] : Wr0[d * 64 + (k - 64)];
                wt[i] = f2bs(v);
            }
        }
        return;
    }
    int i = b * 256 + t;
    int v = 0;
    if (i < N_NODES) {
        int sum = 0;
        #pragma unroll 5
        for (int c = 0; c < NHB; ++c) {
            long off = (long)c * (HWORDS * 4) + i;
            int u = bhb[off];
            bhb[off] = (unsigned char)sum;   // exclusive base for segment c
            sum += u;
        }
        degi[i] = sum;                       // total degree
        v = sum;
    }
    sc[t] = v;
    __syncthreads();
    #pragma unroll
    for (int off = 1; off < 256; off <<= 1) {
        int u = (t >= off) ? sc[t - off] : 0;
        __syncthreads();
        sc[t] += u;
        __syncthreads();
    }
    if (i < N_NODES) rowstart[i] = sc[t] - v;   // exclusive within block
    if (t == 255) chsum[b] = sc[t];             // RAW chunk sum
}

// fill: prologue scans chsum[391] -> exclusive bsumL in LDS (block 0 also
// persists global bsum for agg/final); then per-(segment,half) reload bases
// into LDS as counter INITIAL values; ds_add_rtn per in-range edge yields
// base+rank directly. Pure LDS atomics; global scatter only for csr.
__global__ __launch_bounds__(HTHREADS) void fill_kernel(const int* __restrict__ ei,
                                                        const int* __restrict__ rowstart,
                                                        const int* __restrict__ chsum,
                                                        int* __restrict__ bsum,
                                                        const unsigned int* __restrict__ bh32,
                                                        int* __restrict__ csr) {
    __shared__ unsigned int cnt[HWORDS_HALF];
    __shared__ int sc[512];
    __shared__ int bsumL[SCAN_BLOCKS];
    const int t = threadIdx.x;
    const int seg = blockIdx.x >> 1, half = blockIdx.x & 1;
    const int nlo = half * HALF_NODES, nhi = nlo + HALF_NODES;

    // prologue: redundant exclusive scan of the 391 chunk sums
    int v0 = 0;
    if (t < 512) {
        v0 = (t < SCAN_BLOCKS) ? chsum[t] : 0;
        sc[t] = v0;
    }
    __syncthreads();
    #pragma unroll
    for (int off = 1; off < 512; off <<= 1) {
        int u = 0;
        if (t < 512 && t >= off) u = sc[t - off];
        __syncthreads();
        if (t < 512) sc[t] += u;
        __syncthreads();
    }
    if (t < SCAN_BLOCKS) {
        bsumL[t] = sc[t] - v0;
        if (blockIdx.x == 0) bsum[t] = sc[t] - v0;   // persist for agg/final
    }
    // (no extra barrier needed before cnt load loop writes; barrier below)

    const unsigned int* in = bh32 + (long)seg * HWORDS + half * HWORDS_HALF;
    for (int w = t; w < HWORDS_HALF; w += HTHREADS) cnt[w] = in[w];
    __syncthreads();
    const int4* srcp4 = (const int4*)(ei + seg * EPB);
    const int4* dstp4 = (const int4*)(ei + N_EDGES + seg * EPB);
    for (int k = t; k < EPB / 4; k += HTHREADS) {
        int4 s4 = srcp4[k];
        int4 d4 = dstp4[k];
        int d, ld, sv;
        unsigned int old;
        d = clampN(d4.x);
        if (d >= nlo && d < nhi) {
            ld = d - nlo; sv = clampN(s4.x);
            old = atomicAdd(&cnt[ld >> 2], 1u << (8 * (ld & 3)));
            csr[rowstart[d] + bsumL[d >> 8] + (int)((old >> (8 * (ld & 3))) & 0xffu)] = sv;
        }
        d = clampN(d4.y);
        if (d >= nlo && d < nhi) {
            ld = d - nlo; sv = clampN(s4.y);
            old = atomicAdd(&cnt[ld >> 2], 1u << (8 * (ld & 3)));
            csr[rowstart[d] + bsumL[d >> 8] + (int)((old >> (8 * (ld & 3))) & 0xffu)] = sv;
        }
        d = clampN(d4.z);
        if (d >= nlo && d < nhi) {
            ld = d - nlo; sv = clampN(s4.z);
            old = atomicAdd(&cnt[ld >> 2], 1u << (8 * (ld & 3)));
            csr[rowstart[d] + bsumL[d >> 8] + (int)((old >> (8 * (ld & 3))) & 0xffu)] = sv;
        }
        d = clampN(d4.w);
        if (d >= nlo && d < nhi) {
            ld = d - nlo; sv = clampN(s4.w);
            old = atomicAdd(&cnt[ld >> 2], 1u << (8 * (ld & 3)));
            csr[rowstart[d] + bsumL[d >> 8] + (int)((old >> (8 * (ld & 3))) & 0xffu)] = sv;
        }
    }
}

// ---------------------------------------------------------------------------
// Fused aggregate + GEMM + heads (R6-proven static form — R8 stealing
// reverted). Block = 256 threads = 16 nodes. Phase 1: 16-lane quarter-wave
// per node; lane owns 4 dims (uint2 = 4 bf16); unroll-8 gather with
// software-pipelined csr index prefetch; bf16 mean -> LDS As[16][AGPAD].
// Phase 2: wave w computes output dims d = w*16 + (lane&15) via 4x
//   mfma_f32_16x16x32_bf16 over K=128 = [mean | x]; C/D: node = quad*4+reg,
//   d = lane&15 (R9-verified). Epilogue: relu, dual head dots, 16-lane shfl
//   reduce over d, LDS-atomic combine across the 4 waves.
// ---------------------------------------------------------------------------
__global__ __launch_bounds__(256) void agg_gemm_kernel(
        const uint2* __restrict__ xb2, const short* __restrict__ xb,
        const short* __restrict__ wt,
        const int* __restrict__ rowstart, const int* __restrict__ bsum,
        const int* __restrict__ degi, const int* __restrict__ csr,
        const float* __restrict__ bl0, const float* __restrict__ Wl1,
        const float* __restrict__ Wr1,
        float* __restrict__ s, float* __restrict__ t) {
    __shared__ short As[16 * AGPAD];
    __shared__ float sRed[16], tRed[16];
    const int tid = threadIdx.x;
    const int nb = blockIdx.x * 16;          // 100000 = 6250*16, always full

    if (tid < 16) { sRed[tid] = 0.0f; tRed[tid] = 0.0f; }

    // ---- phase 1: aggregate (unroll-8, pipelined indices) ----
    {
        int qn = tid >> 4;     // node-local 0..15
        int l  = tid & 15;     // lane in quarter: dims 4l..4l+3
        int n = nb + qn;
        int beg = rowstart[n] + bsum[n >> 8];
        int cnt = degi[n];
        float4 A0 = make_float4(0.f, 0.f, 0.f, 0.f);
        float4 A1 = A0, A2 = A0, A3 = A0;
        int i = 0;
        if (cnt >= 8) {
            const int* cp = csr + beg;
            int e0 = cp[0], e1 = cp[1], e2 = cp[2], e3 = cp[3];
            int e4 = cp[4], e5 = cp[5], e6 = cp[6], e7 = cp[7];
            for (;;) {
                // 8 row-gathers in flight
                uint2 u0 = xb2[(long)e0 * 16 + l];
                uint2 u1 = xb2[(long)e1 * 16 + l];
                uint2 u2 = xb2[(long)e2 * 16 + l];
                uint2 u3 = xb2[(long)e3 * 16 + l];
                uint2 u4 = xb2[(long)e4 * 16 + l];
                uint2 u5 = xb2[(long)e5 * 16 + l];
                uint2 u6 = xb2[(long)e6 * 16 + l];
                uint2 u7 = xb2[(long)e7 * 16 + l];
                // prefetch next 8 indices while gathers are outstanding
                int ni = i + 8;
                bool more = (ni + 8 <= cnt);
                int f0, f1, f2, f3, f4, f5, f6, f7;
                if (more) {
                    const int* np = csr + beg + ni;
                    f0 = np[0]; f1 = np[1]; f2 = np[2]; f3 = np[3];
                    f4 = np[4]; f5 = np[5]; f6 = np[6]; f7 = np[7];
                }
                float2 f;
                f = upk(u0.x); A0.x += f.x; A0.y += f.y; f = upk(u0.y); A0.z += f.x; A0.w += f.y;
                f = upk(u1.x); A1.x += f.x; A1.y += f.y; f = upk(u1.y); A1.z += f.x; A1.w += f.y;
                f = upk(u2.x); A2.x += f.x; A2.y += f.y; f = upk(u2.y); A2.z += f.x; A2.w += f.y;
                f = upk(u3.x); A3.x += f.x; A3.y += f.y; f = upk(u3.y); A3.z += f.x; A3.w += f.y;
                f = upk(u4.x); A0.x += f.x; A0.y += f.y; f = upk(u4.y); A0.z += f.x; A0.w += f.y;
                f = upk(u5.x); A1.x += f.x; A1.y += f.y; f = upk(u5.y); A1.z += f.x; A1.w += f.y;
                f = upk(u6.x); A2.x += f.x; A2.y += f.y; f = upk(u6.y); A2.z += f.x; A2.w += f.y;
                f = upk(u7.x); A3.x += f.x; A3.y += f.y; f = upk(u7.y); A3.z += f.x; A3.w += f.y;
                i = ni;
                if (!more) break;
                e0 = f0; e1 = f1; e2 = f2; e3 = f3;
                e4 = f4; e5 = f5; e6 = f6; e7 = f7;
            }
        }
        if (i + 4 <= cnt) {
            int e0 = csr[beg + i],     e1 = csr[beg + i + 1];
            int e2 = csr[beg + i + 2], e3 = csr[beg + i + 3];
            uint2 u0 = xb2[(long)e0 * 16 + l];
            uint2 u1 = xb2[(long)e1 * 16 + l];
            uint2 u2 = xb2[(long)e2 * 16 + l];
            uint2 u3 = xb2[(long)e3 * 16 + l];
            float2 f;
            f = upk(u0.x); A0.x += f.x; A0.y += f.y; f = upk(u0.y); A0.z += f.x; A0.w += f.y;
            f = upk(u1.x); A1.x += f.x; A1.y += f.y; f = upk(u1.y); A1.z += f.x; A1.w += f.y;
            f = upk(u2.x); A2.x += f.x; A2.y += f.y; f = upk(u2.y); A2.z += f.x; A2.w += f.y;
            f = upk(u3.x); A3.x += f.x; A3.y += f.y; f = upk(u3.y); A3.z += f.x; A3.w += f.y;
            i += 4;
        }
        if (i < cnt) {
            uint2 u = xb2[(long)csr[beg + i] * 16 + l];
            float2 f = upk(u.x); A0.x += f.x; A0.y += f.y;
            f = upk(u.y); A0.z += f.x; A0.w += f.y;
        }
        if (i + 1 < cnt) {
            uint2 u = xb2[(long)csr[beg + i + 1] * 16 + l];
            float2 f = upk(u.x); A1.x += f.x; A1.y += f.y;
            f = upk(u.y); A1.z += f.x; A1.w += f.y;
        }
        if (i + 2 < cnt) {
            uint2 u = xb2[(long)csr[beg + i + 2] * 16 + l];
            float2 f = upk(u.x); A2.x += f.x; A2.y += f.y;
            f = upk(u.y); A2.z += f.x; A2.w += f.y;
        }
        float inv = 1.0f / fmaxf((float)cnt, 1.0f);
        float ax = (A0.x + A1.x + A2.x + A3.x) * inv;
        float ay = (A0.y + A1.y + A2.y + A3.y) * inv;
        float az = (A0.z + A1.z + A2.z + A3.z) * inv;
        float aw = (A0.w + A1.w + A2.w + A3.w) * inv;
        *(uint2*)&As[qn * AGPAD + 4 * l] =
            make_uint2(packbf2(ax, ay), packbf2(az, aw));
    }
    __syncthreads();

    // ---- phase 2: MFMA + heads ----
    const int lane = tid & 63;
    const int w = tid >> 6;
    const int r = lane & 15;
    const int quad = lane >> 4;

    short8 a0 = *(const short8*)&As[r * AGPAD + quad * 8];        // k  0..31
    short8 a1 = *(const short8*)&As[r * AGPAD + 32 + quad * 8];   // k 32..63
    const long xrow = (long)(nb + r) * 64 + quad * 8;
    short8 a2 = *(const short8*)(xb + xrow);                      // k 64..95
    short8 a3 = *(const short8*)(xb + xrow + 32);                 // k 96..127

    const int d = w * 16 + r;
    const short* brow = wt + (long)d * 128 + quad * 8;
    short8 b0 = *(const short8*)(brow);
    short8 b1 = *(const short8*)(brow + 32);
    short8 b2 = *(const short8*)(brow + 64);
    short8 b3 = *(const short8*)(brow + 96);

    float bb = bl0[d];
    floatx4 acc = {bb, bb, bb, bb};
    acc = __builtin_amdgcn_mfma_f32_16x16x32_bf16(a0, b0, acc, 0, 0, 0);
    acc = __builtin_amdgcn_mfma_f32_16x16x32_bf16(a1, b1, acc, 0, 0, 0);
    acc = __builtin_amdgcn_mfma_f32_16x16x32_bf16(a2, b2, acc, 0, 0, 0);
    acc = __builtin_amdgcn_mfma_f32_16x16x32_bf16(a3, b3, acc, 0, 0, 0);

    float w1 = Wl1[d], w2 = Wr1[d];
    float hs[4], ht[4];
    #pragma unroll
    for (int g = 0; g < 4; ++g) {
        float h = fmaxf(acc[g], 0.0f);
        hs[g] = h * w1;
        ht[g] = h * w2;
    }
    #pragma unroll
    for (int g = 0; g < 4; ++g) {
        #pragma unroll
        for (int off = 1; off < 16; off <<= 1) {
            hs[g] += __shfl_xor(hs[g], off, 64);
            ht[g] += __shfl_xor(ht[g], off, 64);
        }
    }
    if (r == 0) {
        #pragma unroll
        for (int g = 0; g < 4; ++g) {
            atomicAdd(&sRed[quad * 4 + g], hs[g]);
            atomicAdd(&tRed[quad * 4 + g], ht[g]);
        }
    }
    __syncthreads();
    if (tid < 16) {
        s[nb + tid] = sRed[tid];
        t[nb + tid] = tRed[tid];
    }
}

// ---------------------------------------------------------------------------
// Final: CSR-gather of s (8-wide ILP), mean, + bl1 + t, sigmoid, fp32 out.
// ---------------------------------------------------------------------------
__global__ void final_kernel(const float* __restrict__ s,
                             const float* __restrict__ t,
                             const int* __restrict__ rowstart,
                             const int* __restrict__ bsum,
                             const int* __restrict__ degi,
                             const int* __restrict__ csr,
                             const float* __restrict__ bl1,
                             float* __restrict__ out) {
    int n = blockIdx.x * 256 + threadIdx.x;
    if (n >= N_NODES) return;
    int beg = rowstart[n] + bsum[n >> 8];
    int cnt = degi[n];
    float acc = 0.0f;
    int i = 0;
    for (; i + 8 <= cnt; i += 8) {
        int e0 = csr[beg + i],     e1 = csr[beg + i + 1];
        int e2 = csr[beg + i + 2], e3 = csr[beg + i + 3];
        int e4 = csr[beg + i + 4], e5 = csr[beg + i + 5];
        int e6 = csr[beg + i + 6], e7 = csr[beg + i + 7];
        float v0 = s[e0], v1 = s[e1], v2 = s[e2], v3 = s[e3];
        float v4 = s[e4], v5 = s[e5], v6 = s[e6], v7 = s[e7];
        acc += ((v0 + v1) + (v2 + v3)) + ((v4 + v5) + (v6 + v7));
    }
    for (; i + 4 <= cnt; i += 4) {
        int e0 = csr[beg + i], e1 = csr[beg + i + 1];
        int e2 = csr[beg + i + 2], e3 = csr[beg + i + 3];
        acc += s[e0] + s[e1] + s[e2] + s[e3];
    }
    for (; i < cnt; ++i) acc += s[csr[beg + i]];
    float v = acc / fmaxf((float)cnt, 1.0f) + bl1[0] + t[n];
    float sg = 1.0f / (1.0f + expf(-v));
    out[n] = v;
    out[N_NODES + n] = sg;
}

extern "C" void kernel_launch(void* const* d_in, const int* in_sizes, int n_in,
                              void* d_out, int out_size, void* d_ws, size_t ws_size,
                              hipStream_t stream) {
    const float* x   = (const float*)d_in[0];
    const int*   ei  = (const int*)d_in[1];   // int32, [2,E] flat: src row, dst row
    const float* Wl0 = (const float*)d_in[2];
    const float* bl0 = (const float*)d_in[3];
    const float* Wr0 = (const float*)d_in[4];
    const float* Wl1 = (const float*)d_in[5];
    const float* bl1 = (const float*)d_in[6];
    const float* Wr1 = (const float*)d_in[7];
    float* out = (float*)d_out;

    // Workspace layout (~30.9 MB, all offsets 16-B aligned):
    //   degi     @0            (400,000)    written by scan1 (totals)
    //   rowstart @400,000      (400,000)
    //   bsum     @800,000      (2,048)      exclusive chunk bases (agg/final)
    //   chsum    @802,048      (2,048)      raw chunk sums (scan1 -> fill)
    //   s        @804,096      (400,000)
    //   t        @1,204,096    (400,000)
    //   csr      @1,604,096    (4,000,000)
    //   xb       @5,604,096    (12,800,000)  bf16 x rows
    //   wt       @18,404,096   (16,384)      bf16 [Wl0|Wr0] rows
    //   bh       @18,420,480   (12,500,000)  125 per-segment byte histograms
    char* ws = (char*)d_ws;
    int*   degi     = (int*)(ws);
    int*   rowstart = (int*)(ws + 400000);
    int*   bsum     = (int*)(ws + 800000);
    int*   chsum    = (int*)(ws + 802048);
    float* s        = (float*)(ws + 804096);
    float* t        = (float*)(ws + 1204096);
    int*   csr      = (int*)(ws + 1604096);
    char*  xb       = (ws + 5604096);
    short* wt       = (short*)(ws + 18404096);
    char*  bh       = (ws + 18420480);

    count_kernel<<<2 * NHB, HTHREADS, 0, stream>>>(ei, (unsigned int*)bh);
    scan1_convert_kernel<<<SCAN_BLOCKS + 6251, 256, 0, stream>>>(
        (unsigned char*)bh, degi, rowstart, chsum,
        (const float4*)x, (uint2*)xb, Wl0, Wr0, wt);
    fill_kernel<<<2 * NHB, HTHREADS, 0, stream>>>(ei, rowstart, chsum, bsum,
                                                  (const unsigned int*)bh, csr);
    agg_gemm_kernel<<<6250, 256, 0, stream>>>((const uint2*)xb, (const short*)xb,
                                              wt, rowstart, bsum, degi, csr,
                                              bl0, Wl1, Wr1, s, t);
    final_kernel<<<SCAN_BLOCKS, 256, 0, stream>>>(s, t, rowstart, bsum, degi, csr,
                                                  bl1, out);
}